// Round 5
// baseline (1321.343 us; speedup 1.0000x reference)
//
#include <hip/hip_runtime.h>
#include <cfloat>

#define BATCH 4
#define P 8192
#define C 64
#define KNN 16
#define NPTS (BATCH * P)        // 32768
#define NEDGE (NPTS * KNN)      // 524288
#define EPSV 1e-5f
#define SLOPE 0.2f
#define NQ 2                    // column-range split per row-tile
#define QCOLS (P / NQ)          // 4096 cols per block

typedef __attribute__((ext_vector_type(8))) short bf16x8;
typedef __attribute__((ext_vector_type(16))) float f32x16;

// sentinel key = (monof(FLT_MAX)<<32)|0xffffffff : larger than any real key,
// and invmonof(hi32) == FLT_MAX so the float gate stays open while filling.
#define KSENT 0xFF7FFFFFFFFFFFFFull

// ---------------- workspace layout (float element offsets) ----------------
// U      : [NPTS][C]   @ 0          (2097152)   written AFTER knn
// V      : [NPTS][C]   @ 2097152    (2097152)   written AFTER knn
// xfh/xfm/xfl bf16 frags alias U/V region (dead after knn)
// sq     : [NPTS]      @ 4194304    (32768)
// stats  : [128]       @ 4227072
// sshift : [128]       @ 4227200
// idx    : int[NEDGE]  @ 4227328    (524288)
// pv     : [NPTS][NQ][16] float @ 4751616 (1048576)
// pi     : [NPTS][NQ][16] int   @ 5800192 (1048576)
// total = 6848768 floats = 26.1 MB

__device__ __forceinline__ unsigned short f2bf(float f) {
    unsigned u = __float_as_uint(f);
    u += 0x7FFFu + ((u >> 16) & 1u);
    return (unsigned short)(u >> 16);
}
__device__ __forceinline__ float bf2f(unsigned short s) {
    return __uint_as_float(((unsigned)s) << 16);
}
// monotone float<->uint map: monof(a) < monof(b)  <=>  a < b (finite floats)
__device__ __forceinline__ unsigned monof(float f) {
    unsigned u = __float_as_uint(f);
    return u ^ ((unsigned)((int)u >> 31) | 0x80000000u);
}
__device__ __forceinline__ float invmonof(unsigned k) {
    unsigned u = (k & 0x80000000u) ? (k ^ 0x80000000u) : ~k;
    return __uint_as_float(u);
}

// ---------------------------------------------------------------------------
// K0: fragment-layout 3-way bf16 split of x + exact fp32 row norms.
// ---------------------------------------------------------------------------
__global__ void prep_frag(const float* __restrict__ x, uint4* __restrict__ xfh,
                          uint4* __restrict__ xfm, uint4* __restrict__ xfl,
                          float* __restrict__ sq) {
    __shared__ float part[32][9];
    int tid = threadIdx.x;
    int ptl = tid >> 3, j8 = tid & 7;
    int g = blockIdx.x;
    int p = g * 32 + ptl;
    const float4* xp = (const float4*)(x + (size_t)p * C + j8 * 8);
    float4 a = xp[0], b = xp[1];
    float v[8] = {a.x, a.y, a.z, a.w, b.x, b.y, b.z, b.w};
    unsigned short hs[8], ms[8], ls[8];
    float ssum = 0.f;
#pragma unroll
    for (int e = 0; e < 8; ++e) {
        float xv = v[e];
        ssum = fmaf(xv, xv, ssum);
        unsigned short h = f2bf(xv);
        float r1 = xv - bf2f(h);
        unsigned short m = f2bf(r1);
        float r2 = r1 - bf2f(m);
        unsigned short l = f2bf(r2);
        hs[e] = h; ms[e] = m; ls[e] = l;
    }
    int dst = (g * 4 + (j8 >> 1)) * 64 + ptl + 32 * (j8 & 1);
    uint4 ph, pm, pl;
    ph.x = (unsigned)hs[0] | ((unsigned)hs[1] << 16);
    ph.y = (unsigned)hs[2] | ((unsigned)hs[3] << 16);
    ph.z = (unsigned)hs[4] | ((unsigned)hs[5] << 16);
    ph.w = (unsigned)hs[6] | ((unsigned)hs[7] << 16);
    pm.x = (unsigned)ms[0] | ((unsigned)ms[1] << 16);
    pm.y = (unsigned)ms[2] | ((unsigned)ms[3] << 16);
    pm.z = (unsigned)ms[4] | ((unsigned)ms[5] << 16);
    pm.w = (unsigned)ms[6] | ((unsigned)ms[7] << 16);
    pl.x = (unsigned)ls[0] | ((unsigned)ls[1] << 16);
    pl.y = (unsigned)ls[2] | ((unsigned)ls[3] << 16);
    pl.z = (unsigned)ls[4] | ((unsigned)ls[5] << 16);
    pl.w = (unsigned)ls[6] | ((unsigned)ls[7] << 16);
    xfh[dst] = ph; xfm[dst] = pm; xfl[dst] = pl;
    part[ptl][j8] = ssum;
    __syncthreads();
    if (j8 == 0) {
        float s = 0.f;
#pragma unroll
        for (int k = 0; k < 8; ++k) s += part[ptl][k];
        sq[p] = s;
    }
}

// exact top-16 insert on u64 keys (mono(value)<<32 | col): (value, index) lex
// order == jax top_k stable tie-break. Static indexing only (rule #20).
#define TRYINSK(KV)                                                           \
    if ((KV) < worstk) {                                                      \
        unsigned long long mx = tk[0]; int pos = 0;                           \
        _Pragma("unroll")                                                     \
        for (int j = 1; j < 16; ++j) {                                        \
            bool g = tk[j] > mx; mx = g ? tk[j] : mx; pos = g ? j : pos;      \
        }                                                                     \
        _Pragma("unroll")                                                     \
        for (int j = 0; j < 16; ++j)                                          \
            if (j == pos) tk[j] = (KV);                                       \
        unsigned long long nw = tk[0];                                        \
        _Pragma("unroll")                                                     \
        for (int j = 1; j < 16; ++j) nw = (tk[j] > nw) ? tk[j] : nw;          \
        worstk = nw;                                                          \
    }

// hot-loop variant: also refresh the float gate (only inside the rare branch)
#define TRYINSKW(KV)                                                          \
    if ((KV) < worstk) {                                                      \
        unsigned long long mx = tk[0]; int pos = 0;                           \
        _Pragma("unroll")                                                     \
        for (int j = 1; j < 16; ++j) {                                        \
            bool g = tk[j] > mx; mx = g ? tk[j] : mx; pos = g ? j : pos;      \
        }                                                                     \
        _Pragma("unroll")                                                     \
        for (int j = 0; j < 16; ++j)                                          \
            if (j == pos) tk[j] = (KV);                                       \
        unsigned long long nw = tk[0];                                        \
        _Pragma("unroll")                                                     \
        for (int j = 1; j < 16; ++j) nw = (tk[j] > nw) ? tk[j] : nw;          \
        worstk = nw;                                                          \
        worstf = invmonof((unsigned)(worstk >> 32));                          \
    }

// ---------------------------------------------------------------------------
// K1: KNN r11 — transposed MFMA output, pure-register per-lane top-16.
//
// r10 post-mortem: failed on a missing bglob offset in the stored column id
// (batches 1-3 indexed batch-0 V rows). Layout math was correct. r11 fixes
// the id and switches all selection to exact u64 keys (mono(value)<<32|col)
// so value-ties break by lowest index everywhere (r10's interleaved per-lane
// lists broke the implicit column-order tie-handling of earlier rounds).
//
// Structure (unchanged from r10): mfma(colfrag, rowfrag) -> lane l owns row
// (l&31), cols {(reg&3)+8*(reg>>2)+4*(l>>5)} per 32-col chunk. Per-lane
// register top-16 over a private 1024-col stream. Main loop: zero LDS, zero
// barriers, zero atomics. sq_row dropped (constant shift per row, rank-
// invariant; pv stores s' = sq_col - 2 x.y, consistent within a row which is
// all merge_kernel compares). Block end: 4 lists/row merged via LDS (2
// stages), then pv/pi; merge_kernel folds the NQ=2 halves.
// ---------------------------------------------------------------------------
__global__ __launch_bounds__(256, 2) void knn_kernel(const uint4* __restrict__ xfh,
                                                     const uint4* __restrict__ xfm,
                                                     const uint4* __restrict__ xfl,
                                                     const float* __restrict__ sq,
                                                     float* __restrict__ pv,
                                                     int* __restrict__ pi) {
    __shared__ unsigned long long fink[64][65];   // [row][list*16+j]

    int tid = threadIdx.x;
    int b = blockIdx.x & 3;              // batch -> XCDs {b, b+4}: frags L2-resident
    int t = blockIdx.x >> 2;
    int tile = t & 127;
    int half = t >> 7;
    int bglob = b * P;
    int r0 = tile * 64;
    int w = tid >> 6, lane = tid & 63;
    int wr = w & 1, wc = w >> 1;
    int hi = lane >> 5;                  // col-offset selector (+4)
    int rloc = lane & 31;                // row owned by this lane (within wave tile)

    // persistent ROW fragments ("B" operand): rows r0 + 32*wr .. +32
    int gA = ((bglob + r0) >> 5) + wr;
    bf16x8 Rh[4], Rm[4], Rl[4];
#pragma unroll
    for (int kk = 0; kk < 4; ++kk) {
        Rh[kk] = __builtin_bit_cast(bf16x8, xfh[(gA * 4 + kk) * 64 + lane]);
        Rm[kk] = __builtin_bit_cast(bf16x8, xfm[(gA * 4 + kk) * 64 + lane]);
        Rl[kk] = __builtin_bit_cast(bf16x8, xfl[(gA * 4 + kk) * 64 + lane]);
    }

    // per-lane register top-16 as u64 keys; worstk = max(tk); worstf = its value
    unsigned long long tk[16];
#pragma unroll
    for (int j = 0; j < 16; ++j) tk[j] = KSENT;
    unsigned long long worstk = KSENT;
    float worstf = FLT_MAX;

    int cw0 = half * QCOLS + wc * 2048;  // this wave's 2048-col range (64 chunks x 32)

    for (int chunk = 0; chunk < 64; ++chunk) {
        int c0 = cw0 + chunk * 32;
        int gB = (bglob + c0) >> 5;
        const uint4* ch = &xfh[(gB * 4) * 64 + lane];
        const uint4* cm = &xfm[(gB * 4) * 64 + lane];
        const uint4* cl = &xfl[(gB * 4) * 64 + lane];

        f32x16 acc0, acc1;
#pragma unroll
        for (int i = 0; i < 16; ++i) { acc0[i] = 0.f; acc1[i] = 0.f; }
#pragma unroll
        for (int kk = 0; kk < 4; ++kk) {
            bf16x8 Ch = __builtin_bit_cast(bf16x8, ch[kk * 64]);
            bf16x8 Cm = __builtin_bit_cast(bf16x8, cm[kk * 64]);
            bf16x8 Cl = __builtin_bit_cast(bf16x8, cl[kk * 64]);
            acc0 = __builtin_amdgcn_mfma_f32_32x32x16_bf16(Ch, Rh[kk], acc0, 0, 0, 0);
            acc1 = __builtin_amdgcn_mfma_f32_32x32x16_bf16(Ch, Rm[kk], acc1, 0, 0, 0);
            acc0 = __builtin_amdgcn_mfma_f32_32x32x16_bf16(Cm, Rh[kk], acc0, 0, 0, 0);
            acc1 = __builtin_amdgcn_mfma_f32_32x32x16_bf16(Cm, Rm[kk], acc1, 0, 0, 0);
            acc0 = __builtin_amdgcn_mfma_f32_32x32x16_bf16(Ch, Rl[kk], acc0, 0, 0, 0);
            acc1 = __builtin_amdgcn_mfma_f32_32x32x16_bf16(Cl, Rh[kk], acc1, 0, 0, 0);
        }

        // col norms for this lane's 16 cols (uniform per half-wave, L1-hit)
        int cb = c0 + 4 * hi;
        float4 sqA[4];
#pragma unroll
        for (int g4 = 0; g4 < 4; ++g4)
            sqA[g4] = *(const float4*)(&sq[bglob + cb + g4 * 8]);
        int bgc = bglob + cb;            // GLOBAL col id base (r10 bug: missing bglob)

        // s' = sq_col - 2 x.y  (sq_row dropped: constant shift per row)
#pragma unroll
        for (int reg = 0; reg < 16; ++reg) {
            float s = fmaf(-2.f, acc0[reg] + acc1[reg],
                           ((const float*)&sqA[reg >> 2])[reg & 3]);
            if (s <= worstf) {           // float gate (common path: 1 cmp)
                int cgl = bgc + (reg & 3) + 8 * (reg >> 2);
                unsigned long long key =
                    ((unsigned long long)monof(s) << 32) | (unsigned)cgl;
                TRYINSKW(key)
            }
        }
    }

    // ---- block-end merge: 4 lists/row -> 1 list/row, then pv/pi ----
    {
        int rowl = 32 * wr + rloc;
        int li = wc * 2 + hi;            // list index 0..3
#pragma unroll
        for (int j = 0; j < 16; ++j) fink[rowl][li * 16 + j] = tk[j];
    }
    __syncthreads();
    if (tid < 128) {                     // stage 1: merge list pairs (0,1) and (2,3)
        int row = tid & 63, pr = tid >> 6;
        int base = pr * 32;
        unsigned long long tk[16];
#pragma unroll
        for (int j = 0; j < 16; ++j) tk[j] = fink[row][base + j];
        unsigned long long worstk = tk[0];
#pragma unroll
        for (int j = 1; j < 16; ++j) worstk = (tk[j] > worstk) ? tk[j] : worstk;
        for (int e = 0; e < 16; ++e) {
            unsigned long long k = fink[row][base + 16 + e];
            TRYINSK(k)
        }
#pragma unroll
        for (int j = 0; j < 16; ++j) fink[row][base + j] = tk[j];
    }
    __syncthreads();
    if (tid < 64) {                      // stage 2: merge (0+1) with (2+3), write out
        int row = tid;
        unsigned long long tk[16];
#pragma unroll
        for (int j = 0; j < 16; ++j) tk[j] = fink[row][j];
        unsigned long long worstk = tk[0];
#pragma unroll
        for (int j = 1; j < 16; ++j) worstk = (tk[j] > worstk) ? tk[j] : worstk;
        for (int e = 0; e < 16; ++e) {
            unsigned long long k = fink[row][32 + e];
            TRYINSK(k)
        }
        size_t o = (((size_t)(bglob + r0 + row)) * NQ + half) * KNN;
#pragma unroll
        for (int j = 0; j < 16; ++j) {
            pv[o + j] = invmonof((unsigned)(tk[j] >> 32));
            pi[o + j] = (int)(unsigned)(tk[j] & 0xFFFFFFFFu);
        }
    }
}

// ---------------------------------------------------------------------------
// K1b: merge NQ=2 partial top-16 lists per row -> final idx (u64-key exact).
// ---------------------------------------------------------------------------
__global__ void merge_kernel(const float* __restrict__ pv, const int* __restrict__ pi,
                             int* __restrict__ idx_out) {
    __shared__ unsigned long long mk[128 * 33];
    int tid = threadIdx.x;
    int lr = tid & 127, q = tid >> 7;
    int row = blockIdx.x * 128 + lr;
    size_t o = ((size_t)row * NQ + q) * KNN;
#pragma unroll
    for (int j = 0; j < 16; ++j) {
        mk[lr * 33 + q * 16 + j] =
            ((unsigned long long)monof(pv[o + j]) << 32) | (unsigned)pi[o + j];
    }
    __syncthreads();
    if (tid < 128) {
        unsigned long long tk[16];
#pragma unroll
        for (int j = 0; j < 16; ++j) tk[j] = mk[tid * 33 + j];
        unsigned long long worstk = tk[0];
#pragma unroll
        for (int j = 1; j < 16; ++j) worstk = (tk[j] > worstk) ? tk[j] : worstk;
        for (int e = 16; e < 32; ++e) {
            unsigned long long k = mk[tid * 33 + e];
            TRYINSK(k)
        }
        size_t oo = (size_t)tid * KNN + (size_t)blockIdx.x * 128 * KNN;
#pragma unroll
        for (int j = 0; j < 16; ++j)
            idx_out[oo + j] = (int)(unsigned)(tk[j] & 0xFFFFFFFFu);
    }
}

// ---------------------------------------------------------------------------
// K2: U = x @ (W1 - W2), V = x @ W2
// ---------------------------------------------------------------------------
__global__ void prep_UV(const float* __restrict__ x, const float* __restrict__ W,
                        float* __restrict__ U, float* __restrict__ V) {
    __shared__ float Ws[128][64];
    __shared__ float xs[4][64];
    int tid = threadIdx.x;
    for (int i = tid; i < 128 * 64; i += 256) ((float*)Ws)[i] = W[i];
    int p0 = blockIdx.x * 4;
    int r = tid >> 6, c = tid & 63;
    xs[r][c] = x[(size_t)(p0 + r) * C + c];
    __syncthreads();
    float u = 0.f, v = 0.f;
#pragma unroll
    for (int k = 0; k < 64; ++k) {
        float xv = xs[r][k];
        float w1 = Ws[k][c];
        float w2 = Ws[64 + k][c];
        u = fmaf(xv, w1 - w2, u);
        v = fmaf(xv, w2, v);
    }
    size_t o = (size_t)(p0 + r) * C + c;
    U[o] = u;
    V[o] = v;
}

// ---------------------------------------------------------------------------
// K3: BN stats
// ---------------------------------------------------------------------------
__global__ void stats_kernel(const float* __restrict__ U, const float* __restrict__ V,
                             const float* __restrict__ bias, const int* __restrict__ idx,
                             float* __restrict__ stats) {
    int tid = threadIdx.x;
    int c = tid & 63, kk = tid >> 6;
    int p0 = blockIdx.x * 32;
    float bc = bias[c];
    float sum = 0.f, sumsq = 0.f;
    for (int pp = 0; pp < 32; ++pp) {
        int p = p0 + pp;
        float u = U[(size_t)p * C + c] + bc;
#pragma unroll
        for (int k4 = 0; k4 < 4; ++k4) {
            int j = idx[(size_t)p * KNN + kk * 4 + k4];
            float h = u + V[(size_t)j * C + c];
            sum += h;
            sumsq = fmaf(h, h, sumsq);
        }
    }
    __shared__ float red[2][4][64];
    red[0][kk][c] = sum;
    red[1][kk][c] = sumsq;
    __syncthreads();
    if (tid < 64) {
        float s = red[0][0][tid] + red[0][1][tid] + red[0][2][tid] + red[0][3][tid];
        atomicAdd(&stats[tid], s);
    } else if (tid < 128) {
        int cc = tid - 64;
        float s = red[1][0][cc] + red[1][1][cc] + red[1][2][cc] + red[1][3][cc];
        atomicAdd(&stats[64 + cc], s);
    }
}

__global__ void finalize_kernel(const float* __restrict__ stats,
                                const float* __restrict__ gamma,
                                const float* __restrict__ beta,
                                float* __restrict__ sshift) {
    int c = threadIdx.x;
    const float N = (float)NEDGE;
    float mean = stats[c] / N;
    float var = stats[64 + c] / N - mean * mean;
    float s = gamma[c] * rsqrtf(var + EPSV);
    sshift[c] = s;
    sshift[64 + c] = beta[c] - mean * s;
}

// ---------------------------------------------------------------------------
// K5: out = lrelu(s*(U+b + max/min_k V[idx]) + t)  (monotone fusion of max_k)
// ---------------------------------------------------------------------------
__global__ void out_kernel(const float* __restrict__ U, const float* __restrict__ V,
                           const float* __restrict__ bias, const int* __restrict__ idx,
                           const float* __restrict__ sshift, float* __restrict__ out) {
    int tid = threadIdx.x;
    int c = tid & 63, g = tid >> 6;
    int p0 = blockIdx.x * 16;
    float s = sshift[c], t = sshift[64 + c];
    float bc = bias[c];
    for (int pp = g; pp < 16; pp += 4) {
        int p = p0 + pp;
        float mx = -FLT_MAX, mn = FLT_MAX;
#pragma unroll
        for (int k = 0; k < KNN; ++k) {
            int j = idx[(size_t)p * KNN + k];
            float v = V[(size_t)j * C + c];
            mx = fmaxf(mx, v);
            mn = fminf(mn, v);
        }
        float hsel = (s >= 0.f) ? mx : mn;
        float hn = fmaf(s, U[(size_t)p * C + c] + bc + hsel, t);
        out[(size_t)p * C + c] = (hn >= 0.f) ? hn : SLOPE * hn;
    }
}

// ---------------------------------------------------------------------------
extern "C" void kernel_launch(void* const* d_in, const int* in_sizes, int n_in,
                              void* d_out, int out_size, void* d_ws, size_t ws_size,
                              hipStream_t stream) {
    const float* x     = (const float*)d_in[0];
    const float* W     = (const float*)d_in[2];
    const float* bias  = (const float*)d_in[3];
    const float* gamma = (const float*)d_in[4];
    const float* beta  = (const float*)d_in[5];
    float* out = (float*)d_out;

    float* wsf    = (float*)d_ws;
    float* U      = wsf;
    float* V      = wsf + 2097152;
    uint4* xfh    = (uint4*)wsf;                   // aliases U/V, dead after knn
    uint4* xfm    = (uint4*)(wsf + 1048576);
    uint4* xfl    = (uint4*)(wsf + 2097152);
    float* sq     = wsf + 4194304;
    float* stats  = wsf + 4227072;
    float* sshift = wsf + 4227200;
    int*   idx    = (int*)(wsf + 4227328);
    float* pv     = wsf + 4751616;
    int*   pi     = (int*)(wsf + 5800192);

    hipLaunchKernelGGL(prep_frag, dim3(NPTS / 32), dim3(256), 0, stream, x, xfh, xfm, xfl, sq);
    hipLaunchKernelGGL(knn_kernel, dim3(BATCH * (P / 64) * NQ), dim3(256), 0, stream,
                       (const uint4*)xfh, (const uint4*)xfm, (const uint4*)xfl, sq, pv, pi);
    hipLaunchKernelGGL(merge_kernel, dim3(NPTS / 128), dim3(256), 0, stream, pv, pi, idx);
    hipLaunchKernelGGL(prep_UV, dim3(NPTS / 4), dim3(256), 0, stream, x, W, U, V);
    hipMemsetAsync(stats, 0, 128 * sizeof(float), stream);
    hipLaunchKernelGGL(stats_kernel, dim3(NPTS / 32), dim3(256), 0, stream, U, V, bias, idx, stats);
    hipLaunchKernelGGL(finalize_kernel, dim3(1), dim3(64), 0, stream, stats, gamma, beta, sshift);
    hipLaunchKernelGGL(out_kernel, dim3(NPTS / 16), dim3(256), 0, stream, U, V, bias, idx, sshift, out);
}

// Round 7
// 771.387 us; speedup vs baseline: 1.7129x; 1.7129x over previous
//
#include <hip/hip_runtime.h>
#include <cfloat>

#define BATCH 4
#define P 8192
#define C 64
#define KNN 16
#define NPTS (BATCH * P)        // 32768
#define NEDGE (NPTS * KNN)      // 524288
#define EPSV 1e-5f
#define SLOPE 0.2f
#define NQ 2                    // column-range split per row-tile
#define QCOLS (P / NQ)          // 4096 cols per block

typedef __attribute__((ext_vector_type(8))) short bf16x8;
typedef __attribute__((ext_vector_type(16))) float f32x16;

// ---------------- workspace layout (float element offsets) ----------------
// U      : [NPTS][C]   @ 0          (2097152)   written AFTER knn
// V      : [NPTS][C]   @ 2097152    (2097152)   written AFTER knn
// xfh/xfm/xfl bf16 frags alias U/V region (dead after knn)
// sq     : [NPTS]      @ 4194304    (32768)
// stats  : [128]       @ 4227072
// sshift : [128]       @ 4227200
// idx    : int[NEDGE]  @ 4227328    (524288)
// pv     : [NPTS][NQ][16] float @ 4751616 (1048576)
// pi     : [NPTS][NQ][16] int   @ 5800192 (1048576)
// total = 6848768 floats = 26.1 MB

__device__ __forceinline__ unsigned short f2bf(float f) {
    unsigned u = __float_as_uint(f);
    u += 0x7FFFu + ((u >> 16) & 1u);
    return (unsigned short)(u >> 16);
}
__device__ __forceinline__ float bf2f(unsigned short s) {
    return __uint_as_float(((unsigned)s) << 16);
}
// monotone float<->uint map: monof(a) < monof(b)  <=>  a < b (finite floats)
__device__ __forceinline__ unsigned monof(float f) {
    unsigned u = __float_as_uint(f);
    return u ^ ((unsigned)((int)u >> 31) | 0x80000000u);
}
__device__ __forceinline__ float invmonof(unsigned k) {
    unsigned u = (k & 0x80000000u) ? (k ^ 0x80000000u) : ~k;
    return __uint_as_float(u);
}

// ---------------------------------------------------------------------------
// K0: fragment-layout 3-way bf16 split of x + exact fp32 row norms.
// ---------------------------------------------------------------------------
__global__ void prep_frag(const float* __restrict__ x, uint4* __restrict__ xfh,
                          uint4* __restrict__ xfm, uint4* __restrict__ xfl,
                          float* __restrict__ sq) {
    __shared__ float part[32][9];
    int tid = threadIdx.x;
    int ptl = tid >> 3, j8 = tid & 7;
    int g = blockIdx.x;
    int p = g * 32 + ptl;
    const float4* xp = (const float4*)(x + (size_t)p * C + j8 * 8);
    float4 a = xp[0], b = xp[1];
    float v[8] = {a.x, a.y, a.z, a.w, b.x, b.y, b.z, b.w};
    unsigned short hs[8], ms[8], ls[8];
    float ssum = 0.f;
#pragma unroll
    for (int e = 0; e < 8; ++e) {
        float xv = v[e];
        ssum = fmaf(xv, xv, ssum);
        unsigned short h = f2bf(xv);
        float r1 = xv - bf2f(h);
        unsigned short m = f2bf(r1);
        float r2 = r1 - bf2f(m);
        unsigned short l = f2bf(r2);
        hs[e] = h; ms[e] = m; ls[e] = l;
    }
    int dst = (g * 4 + (j8 >> 1)) * 64 + ptl + 32 * (j8 & 1);
    uint4 ph, pm, pl;
    ph.x = (unsigned)hs[0] | ((unsigned)hs[1] << 16);
    ph.y = (unsigned)hs[2] | ((unsigned)hs[3] << 16);
    ph.z = (unsigned)hs[4] | ((unsigned)hs[5] << 16);
    ph.w = (unsigned)hs[6] | ((unsigned)hs[7] << 16);
    pm.x = (unsigned)ms[0] | ((unsigned)ms[1] << 16);
    pm.y = (unsigned)ms[2] | ((unsigned)ms[3] << 16);
    pm.z = (unsigned)ms[4] | ((unsigned)ms[5] << 16);
    pm.w = (unsigned)ms[6] | ((unsigned)ms[7] << 16);
    pl.x = (unsigned)ls[0] | ((unsigned)ls[1] << 16);
    pl.y = (unsigned)ls[2] | ((unsigned)ls[3] << 16);
    pl.z = (unsigned)ls[4] | ((unsigned)ls[5] << 16);
    pl.w = (unsigned)ls[6] | ((unsigned)ls[7] << 16);
    xfh[dst] = ph; xfm[dst] = pm; xfl[dst] = pl;
    part[ptl][j8] = ssum;
    __syncthreads();
    if (j8 == 0) {
        float s = 0.f;
#pragma unroll
        for (int k = 0; k < 8; ++k) s += part[ptl][k];
        sq[p] = s;
    }
}

// sorted-shift insert into ASC tv[16]/ti[16]: precomputed bools, descending
// in-place shift, all-static indexing, ~85 independent VALU. Strict '<':
// equal values keep the earlier-inserted (lower stream position).
#define SORTED_INS16(MV, IDV)                                                  \
    {                                                                          \
        float _m = (MV); int _id = (IDV);                                      \
        bool c0 = _m < tv[0], c1 = _m < tv[1], c2 = _m < tv[2],                \
             c3 = _m < tv[3], c4 = _m < tv[4], c5 = _m < tv[5],                \
             c6 = _m < tv[6], c7 = _m < tv[7], c8 = _m < tv[8],                \
             c9 = _m < tv[9], c10 = _m < tv[10], c11 = _m < tv[11],            \
             c12 = _m < tv[12], c13 = _m < tv[13], c14 = _m < tv[14],          \
             c15 = _m < tv[15];                                                \
        tv[15] = c15 ? (c14 ? tv[14] : _m) : tv[15];                           \
        ti[15] = c15 ? (c14 ? ti[14] : _id) : ti[15];                          \
        tv[14] = c14 ? (c13 ? tv[13] : _m) : tv[14];                           \
        ti[14] = c14 ? (c13 ? ti[13] : _id) : ti[14];                          \
        tv[13] = c13 ? (c12 ? tv[12] : _m) : tv[13];                           \
        ti[13] = c13 ? (c12 ? ti[12] : _id) : ti[13];                          \
        tv[12] = c12 ? (c11 ? tv[11] : _m) : tv[12];                           \
        ti[12] = c12 ? (c11 ? ti[11] : _id) : ti[12];                          \
        tv[11] = c11 ? (c10 ? tv[10] : _m) : tv[11];                           \
        ti[11] = c11 ? (c10 ? ti[10] : _id) : ti[11];                          \
        tv[10] = c10 ? (c9 ? tv[9] : _m) : tv[10];                             \
        ti[10] = c10 ? (c9 ? ti[9] : _id) : ti[10];                            \
        tv[9] = c9 ? (c8 ? tv[8] : _m) : tv[9];                                \
        ti[9] = c9 ? (c8 ? ti[8] : _id) : ti[9];                               \
        tv[8] = c8 ? (c7 ? tv[7] : _m) : tv[8];                                \
        ti[8] = c8 ? (c7 ? ti[7] : _id) : ti[8];                               \
        tv[7] = c7 ? (c6 ? tv[6] : _m) : tv[7];                                \
        ti[7] = c7 ? (c6 ? ti[6] : _id) : ti[7];                               \
        tv[6] = c6 ? (c5 ? tv[5] : _m) : tv[6];                                \
        ti[6] = c6 ? (c5 ? ti[5] : _id) : ti[6];                               \
        tv[5] = c5 ? (c4 ? tv[4] : _m) : tv[5];                                \
        ti[5] = c5 ? (c4 ? ti[4] : _id) : ti[5];                               \
        tv[4] = c4 ? (c3 ? tv[3] : _m) : tv[4];                                \
        ti[4] = c4 ? (c3 ? ti[3] : _id) : ti[4];                               \
        tv[3] = c3 ? (c2 ? tv[2] : _m) : tv[3];                                \
        ti[3] = c3 ? (c2 ? ti[2] : _id) : ti[3];                               \
        tv[2] = c2 ? (c1 ? tv[1] : _m) : tv[2];                                \
        ti[2] = c2 ? (c1 ? ti[1] : _id) : ti[2];                               \
        tv[1] = c1 ? (c0 ? tv[0] : _m) : tv[1];                                \
        ti[1] = c1 ? (c0 ? ti[0] : _id) : ti[1];                               \
        tv[0] = c0 ? _m : tv[0];                                               \
        ti[0] = c0 ? _id : ti[0];                                              \
    }

// drain one item (oldest, q0) from every lane that has one. Self-filtering:
// a stale item >= tv[15] shifts nothing. FIFO order preserves tie semantics.
#define DRAIN_ONE                                                              \
    {                                                                          \
        bool hv = qn > 0;                                                      \
        float dm = hv ? qv0 : FLT_MAX;                                         \
        int di = qi0;                                                          \
        SORTED_INS16(dm, di)                                                   \
        qv0 = qv1; qi0 = qi1;                                                  \
        qn = hv ? qn - 1 : 0;                                                  \
    }

// ---------------------------------------------------------------------------
// K1: KNN r12 — transposed MFMA + per-lane sorted top-16 with 2-deep FIFO.
//
// r11 post-mortem: VALU-throughput-bound, ~70K instr/wave: each passing
// candidate ran a ~150-VALU u64 argmax-insert, executed wave-wide whenever
// ANY lane passed (~450 site-events). Fix the product (events x body):
//  * body: f32 sorted-shift insert (~85 VALU, independent ops, worst=tv[15]
//    free). Exactness: per-lane stream is column-ascending; strict-less +
//    FIFO => (value,index) lex order == jax top_k. Cross-lane/list merges
//    use u64 keys (r11-proven).
//  * events: passing lanes PUSH (9 VALU, static slots) into a 2-deep FIFO;
//    when __any(qn==2) all queued lanes DRAIN ONE in lockstep -> body
//    executions drop to ~110-140 with near-full SIMD efficiency. Drains
//    self-filter, so queue lag never affects correctness.
// Hot loop: zero LDS, zero barriers, zero atomics. (256,4): ~120 unified
// regs, 16 waves/CU.
// ---------------------------------------------------------------------------
__global__ __launch_bounds__(256, 4) void knn_kernel(const uint4* __restrict__ xfh,
                                                     const uint4* __restrict__ xfm,
                                                     const uint4* __restrict__ xfl,
                                                     const float* __restrict__ sq,
                                                     float* __restrict__ pv,
                                                     int* __restrict__ pi) {
    __shared__ unsigned long long fink[64][65];   // [row][list*16+j]

    int tid = threadIdx.x;
    int b = blockIdx.x & 3;              // batch -> XCDs {b, b+4}: frags L2-resident
    int t = blockIdx.x >> 2;
    int tile = t & 127;
    int half = t >> 7;
    int bglob = b * P;
    int r0 = tile * 64;
    int w = tid >> 6, lane = tid & 63;
    int wr = w & 1, wc = w >> 1;
    int hi = lane >> 5;                  // col-offset selector (+4)
    int rloc = lane & 31;                // row owned by this lane (within wave tile)

    // persistent ROW fragments ("B" operand): rows r0 + 32*wr .. +32
    int gA = ((bglob + r0) >> 5) + wr;
    bf16x8 Rh[4], Rm[4], Rl[4];
#pragma unroll
    for (int kk = 0; kk < 4; ++kk) {
        Rh[kk] = __builtin_bit_cast(bf16x8, xfh[(gA * 4 + kk) * 64 + lane]);
        Rm[kk] = __builtin_bit_cast(bf16x8, xfm[(gA * 4 + kk) * 64 + lane]);
        Rl[kk] = __builtin_bit_cast(bf16x8, xfl[(gA * 4 + kk) * 64 + lane]);
    }

    // per-lane sorted top-16 + 2-deep FIFO queue
    float tv[16];
    int   ti[16];
#pragma unroll
    for (int j = 0; j < 16; ++j) { tv[j] = FLT_MAX; ti[j] = 0; }
    float qv0 = FLT_MAX, qv1 = FLT_MAX;
    int   qi0 = 0, qi1 = 0, qn = 0;

    int cw0 = half * QCOLS + wc * 2048;  // this wave's 2048-col range (64 chunks x 32)

    for (int chunk = 0; chunk < 64; ++chunk) {
        int c0 = cw0 + chunk * 32;
        int gB = (bglob + c0) >> 5;
        const uint4* ch = &xfh[(gB * 4) * 64 + lane];
        const uint4* cm = &xfm[(gB * 4) * 64 + lane];
        const uint4* cl = &xfl[(gB * 4) * 64 + lane];

        f32x16 acc0, acc1;
#pragma unroll
        for (int i = 0; i < 16; ++i) { acc0[i] = 0.f; acc1[i] = 0.f; }
#pragma unroll
        for (int kk = 0; kk < 4; ++kk) {
            bf16x8 Ch = __builtin_bit_cast(bf16x8, ch[kk * 64]);
            bf16x8 Cm = __builtin_bit_cast(bf16x8, cm[kk * 64]);
            bf16x8 Cl = __builtin_bit_cast(bf16x8, cl[kk * 64]);
            acc0 = __builtin_amdgcn_mfma_f32_32x32x16_bf16(Ch, Rh[kk], acc0, 0, 0, 0);
            acc1 = __builtin_amdgcn_mfma_f32_32x32x16_bf16(Ch, Rm[kk], acc1, 0, 0, 0);
            acc0 = __builtin_amdgcn_mfma_f32_32x32x16_bf16(Cm, Rh[kk], acc0, 0, 0, 0);
            acc1 = __builtin_amdgcn_mfma_f32_32x32x16_bf16(Cm, Rm[kk], acc1, 0, 0, 0);
            acc0 = __builtin_amdgcn_mfma_f32_32x32x16_bf16(Ch, Rl[kk], acc0, 0, 0, 0);
            acc1 = __builtin_amdgcn_mfma_f32_32x32x16_bf16(Cl, Rh[kk], acc1, 0, 0, 0);
        }

        // col norms for this lane's 16 cols (uniform per half-wave, L1-hit)
        int cb = c0 + 4 * hi;
        float4 sqA[4];
#pragma unroll
        for (int g4 = 0; g4 < 4; ++g4)
            sqA[g4] = *(const float4*)(&sq[bglob + cb + g4 * 8]);
        int bgc = bglob + cb;            // GLOBAL col id base

        // site loop: s' = sq_col - 2 x.y (sq_row dropped: rank-invariant)
#pragma unroll
        for (int reg = 0; reg < 16; ++reg) {
            float s = fmaf(-2.f, acc0[reg] + acc1[reg],
                           ((const float*)&sqA[reg >> 2])[reg & 3]);
            bool pass = s < tv[15];
            if (pass) {
                int cid = bgc + (reg & 3) + 8 * (reg >> 2);
                if (__any(qn == 2)) { DRAIN_ONE }   // make room (active lanes)
                bool e0 = (qn == 0);
                qv0 = e0 ? s : qv0;  qi0 = e0 ? cid : qi0;
                bool e1 = (qn == 1);
                qv1 = e1 ? s : qv1;  qi1 = e1 ? cid : qi1;
                qn += 1;
            }
        }
    }

    // epilogue: flush queues (qn <= 2)
    DRAIN_ONE
    DRAIN_ONE

    // ---- block-end merge: 4 lists/row -> 1 list/row via u64 keys ----
    {
        int rowl = 32 * wr + rloc;
        int li = wc * 2 + hi;            // list index 0..3
#pragma unroll
        for (int j = 0; j < 16; ++j)
            fink[rowl][li * 16 + j] =
                ((unsigned long long)monof(tv[j]) << 32) | (unsigned)ti[j];
    }
    __syncthreads();
    if (tid < 128) {                     // stage 1: merge list pairs (0,1) and (2,3)
        int row = tid & 63, pr = tid >> 6;
        int base = pr * 32;
        unsigned long long tk[16];
#pragma unroll
        for (int j = 0; j < 16; ++j) tk[j] = fink[row][base + j];
        unsigned long long worstk = tk[0];
#pragma unroll
        for (int j = 1; j < 16; ++j) worstk = (tk[j] > worstk) ? tk[j] : worstk;
        for (int e = 0; e < 16; ++e) {
            unsigned long long k = fink[row][base + 16 + e];
            if (k < worstk) {
                unsigned long long mx = tk[0]; int pos = 0;
#pragma unroll
                for (int j = 1; j < 16; ++j) {
                    bool g = tk[j] > mx; mx = g ? tk[j] : mx; pos = g ? j : pos;
                }
#pragma unroll
                for (int j = 0; j < 16; ++j)
                    if (j == pos) tk[j] = k;
                unsigned long long nw = tk[0];
#pragma unroll
                for (int j = 1; j < 16; ++j) nw = (tk[j] > nw) ? tk[j] : nw;
                worstk = nw;
            }
        }
#pragma unroll
        for (int j = 0; j < 16; ++j) fink[row][base + j] = tk[j];
    }
    __syncthreads();
    if (tid < 64) {                      // stage 2: merge (0+1) with (2+3), write out
        int row = tid;
        unsigned long long tk[16];
#pragma unroll
        for (int j = 0; j < 16; ++j) tk[j] = fink[row][j];
        unsigned long long worstk = tk[0];
#pragma unroll
        for (int j = 1; j < 16; ++j) worstk = (tk[j] > worstk) ? tk[j] : worstk;
        for (int e = 0; e < 16; ++e) {
            unsigned long long k = fink[row][32 + e];
            if (k < worstk) {
                unsigned long long mx = tk[0]; int pos = 0;
#pragma unroll
                for (int j = 1; j < 16; ++j) {
                    bool g = tk[j] > mx; mx = g ? tk[j] : mx; pos = g ? j : pos;
                }
#pragma unroll
                for (int j = 0; j < 16; ++j)
                    if (j == pos) tk[j] = k;
                unsigned long long nw = tk[0];
#pragma unroll
                for (int j = 1; j < 16; ++j) nw = (tk[j] > nw) ? tk[j] : nw;
                worstk = nw;
            }
        }
        size_t o = (((size_t)(bglob + r0 + row)) * NQ + half) * KNN;
#pragma unroll
        for (int j = 0; j < 16; ++j) {
            pv[o + j] = invmonof((unsigned)(tk[j] >> 32));
            pi[o + j] = (int)(unsigned)(tk[j] & 0xFFFFFFFFu);
        }
    }
}

// ---------------------------------------------------------------------------
// K1b: merge NQ=2 partial top-16 lists per row -> final idx (u64-key exact).
// ---------------------------------------------------------------------------
__global__ void merge_kernel(const float* __restrict__ pv, const int* __restrict__ pi,
                             int* __restrict__ idx_out) {
    __shared__ unsigned long long mk[128 * 33];
    int tid = threadIdx.x;
    int lr = tid & 127, q = tid >> 7;
    int row = blockIdx.x * 128 + lr;
    size_t o = ((size_t)row * NQ + q) * KNN;
#pragma unroll
    for (int j = 0; j < 16; ++j) {
        mk[lr * 33 + q * 16 + j] =
            ((unsigned long long)monof(pv[o + j]) << 32) | (unsigned)pi[o + j];
    }
    __syncthreads();
    if (tid < 128) {
        unsigned long long tk[16];
#pragma unroll
        for (int j = 0; j < 16; ++j) tk[j] = mk[tid * 33 + j];
        unsigned long long worstk = tk[0];
#pragma unroll
        for (int j = 1; j < 16; ++j) worstk = (tk[j] > worstk) ? tk[j] : worstk;
        for (int e = 16; e < 32; ++e) {
            unsigned long long k = mk[tid * 33 + e];
            if (k < worstk) {
                unsigned long long mx = tk[0]; int pos = 0;
#pragma unroll
                for (int j = 1; j < 16; ++j) {
                    bool g = tk[j] > mx; mx = g ? tk[j] : mx; pos = g ? j : pos;
                }
#pragma unroll
                for (int j = 0; j < 16; ++j)
                    if (j == pos) tk[j] = k;
                unsigned long long nw = tk[0];
#pragma unroll
                for (int j = 1; j < 16; ++j) nw = (tk[j] > nw) ? tk[j] : nw;
                worstk = nw;
            }
        }
        size_t oo = (size_t)tid * KNN + (size_t)blockIdx.x * 128 * KNN;
#pragma unroll
        for (int j = 0; j < 16; ++j)
            idx_out[oo + j] = (int)(unsigned)(tk[j] & 0xFFFFFFFFu);
    }
}

// ---------------------------------------------------------------------------
// K2: U = x @ (W1 - W2), V = x @ W2
// ---------------------------------------------------------------------------
__global__ void prep_UV(const float* __restrict__ x, const float* __restrict__ W,
                        float* __restrict__ U, float* __restrict__ V) {
    __shared__ float Ws[128][64];
    __shared__ float xs[4][64];
    int tid = threadIdx.x;
    for (int i = tid; i < 128 * 64; i += 256) ((float*)Ws)[i] = W[i];
    int p0 = blockIdx.x * 4;
    int r = tid >> 6, c = tid & 63;
    xs[r][c] = x[(size_t)(p0 + r) * C + c];
    __syncthreads();
    float u = 0.f, v = 0.f;
#pragma unroll
    for (int k = 0; k < 64; ++k) {
        float xv = xs[r][k];
        float w1 = Ws[k][c];
        float w2 = Ws[64 + k][c];
        u = fmaf(xv, w1 - w2, u);
        v = fmaf(xv, w2, v);
    }
    size_t o = (size_t)(p0 + r) * C + c;
    U[o] = u;
    V[o] = v;
}

// ---------------------------------------------------------------------------
// K3: BN stats
// ---------------------------------------------------------------------------
__global__ void stats_kernel(const float* __restrict__ U, const float* __restrict__ V,
                             const float* __restrict__ bias, const int* __restrict__ idx,
                             float* __restrict__ stats) {
    int tid = threadIdx.x;
    int c = tid & 63, kk = tid >> 6;
    int p0 = blockIdx.x * 32;
    float bc = bias[c];
    float sum = 0.f, sumsq = 0.f;
    for (int pp = 0; pp < 32; ++pp) {
        int p = p0 + pp;
        float u = U[(size_t)p * C + c] + bc;
#pragma unroll
        for (int k4 = 0; k4 < 4; ++k4) {
            int j = idx[(size_t)p * KNN + kk * 4 + k4];
            float h = u + V[(size_t)j * C + c];
            sum += h;
            sumsq = fmaf(h, h, sumsq);
        }
    }
    __shared__ float red[2][4][64];
    red[0][kk][c] = sum;
    red[1][kk][c] = sumsq;
    __syncthreads();
    if (tid < 64) {
        float s = red[0][0][tid] + red[0][1][tid] + red[0][2][tid] + red[0][3][tid];
        atomicAdd(&stats[tid], s);
    } else if (tid < 128) {
        int cc = tid - 64;
        float s = red[1][0][cc] + red[1][1][cc] + red[1][2][cc] + red[1][3][cc];
        atomicAdd(&stats[64 + cc], s);
    }
}

__global__ void finalize_kernel(const float* __restrict__ stats,
                                const float* __restrict__ gamma,
                                const float* __restrict__ beta,
                                float* __restrict__ sshift) {
    int c = threadIdx.x;
    const float N = (float)NEDGE;
    float mean = stats[c] / N;
    float var = stats[64 + c] / N - mean * mean;
    float s = gamma[c] * rsqrtf(var + EPSV);
    sshift[c] = s;
    sshift[64 + c] = beta[c] - mean * s;
}

// ---------------------------------------------------------------------------
// K5: out = lrelu(s*(U+b + max/min_k V[idx]) + t)  (monotone fusion of max_k)
// ---------------------------------------------------------------------------
__global__ void out_kernel(const float* __restrict__ U, const float* __restrict__ V,
                           const float* __restrict__ bias, const int* __restrict__ idx,
                           const float* __restrict__ sshift, float* __restrict__ out) {
    int tid = threadIdx.x;
    int c = tid & 63, g = tid >> 6;
    int p0 = blockIdx.x * 16;
    float s = sshift[c], t = sshift[64 + c];
    float bc = bias[c];
    for (int pp = g; pp < 16; pp += 4) {
        int p = p0 + pp;
        float mx = -FLT_MAX, mn = FLT_MAX;
#pragma unroll
        for (int k = 0; k < KNN; ++k) {
            int j = idx[(size_t)p * KNN + k];
            float v = V[(size_t)j * C + c];
            mx = fmaxf(mx, v);
            mn = fminf(mn, v);
        }
        float hsel = (s >= 0.f) ? mx : mn;
        float hn = fmaf(s, U[(size_t)p * C + c] + bc + hsel, t);
        out[(size_t)p * C + c] = (hn >= 0.f) ? hn : SLOPE * hn;
    }
}

// ---------------------------------------------------------------------------
extern "C" void kernel_launch(void* const* d_in, const int* in_sizes, int n_in,
                              void* d_out, int out_size, void* d_ws, size_t ws_size,
                              hipStream_t stream) {
    const float* x     = (const float*)d_in[0];
    const float* W     = (const float*)d_in[2];
    const float* bias  = (const float*)d_in[3];
    const float* gamma = (const float*)d_in[4];
    const float* beta  = (const float*)d_in[5];
    float* out = (float*)d_out;

    float* wsf    = (float*)d_ws;
    float* U      = wsf;
    float* V      = wsf + 2097152;
    uint4* xfh    = (uint4*)wsf;                   // aliases U/V, dead after knn
    uint4* xfm    = (uint4*)(wsf + 1048576);
    uint4* xfl    = (uint4*)(wsf + 2097152);
    float* sq     = wsf + 4194304;
    float* stats  = wsf + 4227072;
    float* sshift = wsf + 4227200;
    int*   idx    = (int*)(wsf + 4227328);
    float* pv     = wsf + 4751616;
    int*   pi     = (int*)(wsf + 5800192);

    hipLaunchKernelGGL(prep_frag, dim3(NPTS / 32), dim3(256), 0, stream, x, xfh, xfm, xfl, sq);
    hipLaunchKernelGGL(knn_kernel, dim3(BATCH * (P / 64) * NQ), dim3(256), 0, stream,
                       (const uint4*)xfh, (const uint4*)xfm, (const uint4*)xfl, sq, pv, pi);
    hipLaunchKernelGGL(merge_kernel, dim3(NPTS / 128), dim3(256), 0, stream, pv, pi, idx);
    hipLaunchKernelGGL(prep_UV, dim3(NPTS / 4), dim3(256), 0, stream, x, W, U, V);
    hipMemsetAsync(stats, 0, 128 * sizeof(float), stream);
    hipLaunchKernelGGL(stats_kernel, dim3(NPTS / 32), dim3(256), 0, stream, U, V, bias, idx, stats);
    hipLaunchKernelGGL(finalize_kernel, dim3(1), dim3(64), 0, stream, stats, gamma, beta, sshift);
    hipLaunchKernelGGL(out_kernel, dim3(NPTS / 16), dim3(256), 0, stream, U, V, bias, idx, sshift, out);
}

// Round 8
// 509.662 us; speedup vs baseline: 2.5926x; 1.5135x over previous
//
#include <hip/hip_runtime.h>
#include <cfloat>

#define BATCH 4
#define P 8192
#define C 64
#define KNN 16
#define NPTS (BATCH * P)        // 32768
#define NEDGE (NPTS * KNN)      // 524288
#define EPSV 1e-5f
#define SLOPE 0.2f
#define NQ 2                    // column-range split per row-tile
#define QCOLS (P / NQ)          // 4096 cols per block
#define QCAP 8                  // lane-private LDS queue depth

typedef __attribute__((ext_vector_type(8))) short bf16x8;
typedef __attribute__((ext_vector_type(16))) float f32x16;

// ---------------- workspace layout (float element offsets) ----------------
// U      : [NPTS][C]   @ 0          (2097152)   written AFTER knn
// V      : [NPTS][C]   @ 2097152    (2097152)   written AFTER knn
// xfh/xfm/xfl bf16 frags alias U/V region (dead after knn)
// sq     : [NPTS]      @ 4194304    (32768)
// stats  : [128]       @ 4227072
// sshift : [128]       @ 4227200
// idx    : int[NEDGE]  @ 4227328    (524288)
// pv     : [NPTS][NQ][16] float @ 4751616 (1048576)
// pi     : [NPTS][NQ][16] int   @ 5800192 (1048576)
// total = 6848768 floats = 26.1 MB

__device__ __forceinline__ unsigned short f2bf(float f) {
    unsigned u = __float_as_uint(f);
    u += 0x7FFFu + ((u >> 16) & 1u);
    return (unsigned short)(u >> 16);
}
__device__ __forceinline__ float bf2f(unsigned short s) {
    return __uint_as_float(((unsigned)s) << 16);
}
// monotone float<->uint map: monof(a) < monof(b)  <=>  a < b (finite floats)
__device__ __forceinline__ unsigned monof(float f) {
    unsigned u = __float_as_uint(f);
    return u ^ ((unsigned)((int)u >> 31) | 0x80000000u);
}
__device__ __forceinline__ float invmonof(unsigned k) {
    unsigned u = (k & 0x80000000u) ? (k ^ 0x80000000u) : ~k;
    return __uint_as_float(u);
}

// ---------------------------------------------------------------------------
// K0: fragment-layout 3-way bf16 split of x + exact fp32 row norms.
// ---------------------------------------------------------------------------
__global__ void prep_frag(const float* __restrict__ x, uint4* __restrict__ xfh,
                          uint4* __restrict__ xfm, uint4* __restrict__ xfl,
                          float* __restrict__ sq) {
    __shared__ float part[32][9];
    int tid = threadIdx.x;
    int ptl = tid >> 3, j8 = tid & 7;
    int g = blockIdx.x;
    int p = g * 32 + ptl;
    const float4* xp = (const float4*)(x + (size_t)p * C + j8 * 8);
    float4 a = xp[0], b = xp[1];
    float v[8] = {a.x, a.y, a.z, a.w, b.x, b.y, b.z, b.w};
    unsigned short hs[8], ms[8], ls[8];
    float ssum = 0.f;
#pragma unroll
    for (int e = 0; e < 8; ++e) {
        float xv = v[e];
        ssum = fmaf(xv, xv, ssum);
        unsigned short h = f2bf(xv);
        float r1 = xv - bf2f(h);
        unsigned short m = f2bf(r1);
        float r2 = r1 - bf2f(m);
        unsigned short l = f2bf(r2);
        hs[e] = h; ms[e] = m; ls[e] = l;
    }
    int dst = (g * 4 + (j8 >> 1)) * 64 + ptl + 32 * (j8 & 1);
    uint4 ph, pm, pl;
    ph.x = (unsigned)hs[0] | ((unsigned)hs[1] << 16);
    ph.y = (unsigned)hs[2] | ((unsigned)hs[3] << 16);
    ph.z = (unsigned)hs[4] | ((unsigned)hs[5] << 16);
    ph.w = (unsigned)hs[6] | ((unsigned)hs[7] << 16);
    pm.x = (unsigned)ms[0] | ((unsigned)ms[1] << 16);
    pm.y = (unsigned)ms[2] | ((unsigned)ms[3] << 16);
    pm.z = (unsigned)ms[4] | ((unsigned)ms[5] << 16);
    pm.w = (unsigned)ms[6] | ((unsigned)ms[7] << 16);
    pl.x = (unsigned)ls[0] | ((unsigned)ls[1] << 16);
    pl.y = (unsigned)ls[2] | ((unsigned)ls[3] << 16);
    pl.z = (unsigned)ls[4] | ((unsigned)ls[5] << 16);
    pl.w = (unsigned)ls[6] | ((unsigned)ls[7] << 16);
    xfh[dst] = ph; xfm[dst] = pm; xfl[dst] = pl;
    part[ptl][j8] = ssum;
    __syncthreads();
    if (j8 == 0) {
        float s = 0.f;
#pragma unroll
        for (int k = 0; k < 8; ++k) s += part[ptl][k];
        sq[p] = s;
    }
}

// sorted-shift insert into ASC tv[16]/ti[16]: precomputed bools, descending
// in-place shift, all-static indexing, ~85 independent VALU. Strict '<':
// equal values keep the earlier-inserted (lower stream position).
#define SORTED_INS16(MV, IDV)                                                  \
    {                                                                          \
        float _m = (MV); int _id = (IDV);                                      \
        bool c0 = _m < tv[0], c1 = _m < tv[1], c2 = _m < tv[2],                \
             c3 = _m < tv[3], c4 = _m < tv[4], c5 = _m < tv[5],                \
             c6 = _m < tv[6], c7 = _m < tv[7], c8 = _m < tv[8],                \
             c9 = _m < tv[9], c10 = _m < tv[10], c11 = _m < tv[11],            \
             c12 = _m < tv[12], c13 = _m < tv[13], c14 = _m < tv[14],          \
             c15 = _m < tv[15];                                                \
        tv[15] = c15 ? (c14 ? tv[14] : _m) : tv[15];                           \
        ti[15] = c15 ? (c14 ? ti[14] : _id) : ti[15];                          \
        tv[14] = c14 ? (c13 ? tv[13] : _m) : tv[14];                           \
        ti[14] = c14 ? (c13 ? ti[13] : _id) : ti[14];                          \
        tv[13] = c13 ? (c12 ? tv[12] : _m) : tv[13];                           \
        ti[13] = c13 ? (c12 ? ti[12] : _id) : ti[13];                          \
        tv[12] = c12 ? (c11 ? tv[11] : _m) : tv[12];                           \
        ti[12] = c12 ? (c11 ? ti[11] : _id) : ti[12];                          \
        tv[11] = c11 ? (c10 ? tv[10] : _m) : tv[11];                           \
        ti[11] = c11 ? (c10 ? ti[10] : _id) : ti[11];                          \
        tv[10] = c10 ? (c9 ? tv[9] : _m) : tv[10];                             \
        ti[10] = c10 ? (c9 ? ti[9] : _id) : ti[10];                            \
        tv[9] = c9 ? (c8 ? tv[8] : _m) : tv[9];                                \
        ti[9] = c9 ? (c8 ? ti[8] : _id) : ti[9];                               \
        tv[8] = c8 ? (c7 ? tv[7] : _m) : tv[8];                                \
        ti[8] = c8 ? (c7 ? ti[7] : _id) : ti[8];                               \
        tv[7] = c7 ? (c6 ? tv[6] : _m) : tv[7];                                \
        ti[7] = c7 ? (c6 ? ti[6] : _id) : ti[7];                               \
        tv[6] = c6 ? (c5 ? tv[5] : _m) : tv[6];                                \
        ti[6] = c6 ? (c5 ? ti[5] : _id) : ti[6];                               \
        tv[5] = c5 ? (c4 ? tv[4] : _m) : tv[5];                                \
        ti[5] = c5 ? (c4 ? ti[4] : _id) : ti[5];                               \
        tv[4] = c4 ? (c3 ? tv[3] : _m) : tv[4];                                \
        ti[4] = c4 ? (c3 ? ti[3] : _id) : ti[4];                               \
        tv[3] = c3 ? (c2 ? tv[2] : _m) : tv[3];                                \
        ti[3] = c3 ? (c2 ? ti[2] : _id) : ti[3];                               \
        tv[2] = c2 ? (c1 ? tv[1] : _m) : tv[2];                                \
        ti[2] = c2 ? (c1 ? ti[1] : _id) : ti[2];                               \
        tv[1] = c1 ? (c0 ? tv[0] : _m) : tv[1];                                \
        ti[1] = c1 ? (c0 ? ti[0] : _id) : ti[1];                               \
        tv[0] = c0 ? _m : tv[0];                                               \
        ti[0] = c0 ? _id : ti[0];                                              \
    }

// wave-uniform drain of the lane-private LDS queues: runtime (non-unrolled)
// QCAP-iteration loop; invalid slots insert FLT_MAX (no-op under strict '<').
// FIFO order = push order = column order -> tie semantics preserved.
#define DRAIN_Q                                                                \
    {                                                                          \
        _Pragma("nounroll")                                                    \
        for (int j = 0; j < QCAP; ++j) {                                       \
            unsigned long long kq = q[j * 256 + tid];                          \
            bool valid = (j < qn);                                             \
            float dv = valid ? __uint_as_float((unsigned)(kq >> 32)) : FLT_MAX;\
            int di = (int)(unsigned)(kq & 0xFFFFFFFFu);                        \
            SORTED_INS16(dv, di)                                               \
        }                                                                      \
        qn = 0;                                                                \
    }

// ---------------------------------------------------------------------------
// K1: KNN r13 — transposed MFMA + register top-16 + lane-private LDS queues.
//
// r12 post-mortem: 2-deep register FIFO drains fired at ~70% of the 1024
// sites (64 lanes make per-lane-rare events wave-certain: p_any ~= 0.995),
// ~170K VALU instr/wave. Queue depth must make drain EVENTS rare, and
// depth > 2 in registers means dynamic indexing (scratch). Fix: the queue
// lives in LDS, lane-private, dynamically indexed (legal there):
//  * layout [QCAP][256] u64 -> at any drain step j, lanes read consecutive
//    u64 (2-way bank aliasing only = free, m136). 16 KB.
//  * hot path per site: s compute (2) + gate (1) + on-pass pack/ds_write/
//    qn++ (~7). No top-16 work in the common path.
//  * drain only when __any(qn == QCAP) BEFORE a push (slot <= QCAP-1
//    guaranteed): wave-uniform runtime loop, ~780 instr; events ~= busiest
//    lane pushes / QCAP ~= 14 per wave. Final drain + barrier at loop end.
//  * queue region is dead before the block-end merge -> aliases fink
//    (33.3 KB total LDS, 4 blocks/CU; grid 1024 = one full residency).
// Expected ~25K VALU instr/wave (vs r12 ~170K).
// ---------------------------------------------------------------------------
__global__ __launch_bounds__(256, 4) void knn_kernel(const uint4* __restrict__ xfh,
                                                     const uint4* __restrict__ xfm,
                                                     const uint4* __restrict__ xfl,
                                                     const float* __restrict__ sq,
                                                     float* __restrict__ pv,
                                                     int* __restrict__ pi) {
    __shared__ unsigned long long smem[64 * 65];   // 33280 B
    unsigned long long* q = smem;                  // queue alias: [QCAP][256]
    unsigned long long (*fink)[65] = (unsigned long long (*)[65])smem;

    int tid = threadIdx.x;
    int b = blockIdx.x & 3;              // batch -> XCDs {b, b+4}: frags L2-resident
    int t = blockIdx.x >> 2;
    int tile = t & 127;
    int half = t >> 7;
    int bglob = b * P;
    int r0 = tile * 64;
    int w = tid >> 6, lane = tid & 63;
    int wr = w & 1, wc = w >> 1;
    int hi = lane >> 5;                  // col-offset selector (+4)
    int rloc = lane & 31;                // row owned by this lane (within wave tile)

    // persistent ROW fragments ("B" operand): rows r0 + 32*wr .. +32
    int gA = ((bglob + r0) >> 5) + wr;
    bf16x8 Rh[4], Rm[4], Rl[4];
#pragma unroll
    for (int kk = 0; kk < 4; ++kk) {
        Rh[kk] = __builtin_bit_cast(bf16x8, xfh[(gA * 4 + kk) * 64 + lane]);
        Rm[kk] = __builtin_bit_cast(bf16x8, xfm[(gA * 4 + kk) * 64 + lane]);
        Rl[kk] = __builtin_bit_cast(bf16x8, xfl[(gA * 4 + kk) * 64 + lane]);
    }

    // per-lane sorted top-16 (ASC) + LDS queue count
    float tv[16];
    int   ti[16];
#pragma unroll
    for (int j = 0; j < 16; ++j) { tv[j] = FLT_MAX; ti[j] = 0; }
    int qn = 0;

    int cw0 = half * QCOLS + wc * 2048;  // this wave's 2048-col range (64 chunks x 32)

    for (int chunk = 0; chunk < 64; ++chunk) {
        int c0 = cw0 + chunk * 32;
        int gB = (bglob + c0) >> 5;
        const uint4* ch = &xfh[(gB * 4) * 64 + lane];
        const uint4* cm = &xfm[(gB * 4) * 64 + lane];
        const uint4* cl = &xfl[(gB * 4) * 64 + lane];

        f32x16 acc0, acc1;
#pragma unroll
        for (int i = 0; i < 16; ++i) { acc0[i] = 0.f; acc1[i] = 0.f; }
#pragma unroll
        for (int kk = 0; kk < 4; ++kk) {
            bf16x8 Ch = __builtin_bit_cast(bf16x8, ch[kk * 64]);
            bf16x8 Cm = __builtin_bit_cast(bf16x8, cm[kk * 64]);
            bf16x8 Cl = __builtin_bit_cast(bf16x8, cl[kk * 64]);
            acc0 = __builtin_amdgcn_mfma_f32_32x32x16_bf16(Ch, Rh[kk], acc0, 0, 0, 0);
            acc1 = __builtin_amdgcn_mfma_f32_32x32x16_bf16(Ch, Rm[kk], acc1, 0, 0, 0);
            acc0 = __builtin_amdgcn_mfma_f32_32x32x16_bf16(Cm, Rh[kk], acc0, 0, 0, 0);
            acc1 = __builtin_amdgcn_mfma_f32_32x32x16_bf16(Cm, Rm[kk], acc1, 0, 0, 0);
            acc0 = __builtin_amdgcn_mfma_f32_32x32x16_bf16(Ch, Rl[kk], acc0, 0, 0, 0);
            acc1 = __builtin_amdgcn_mfma_f32_32x32x16_bf16(Cl, Rh[kk], acc1, 0, 0, 0);
        }

        // col norms for this lane's 16 cols (uniform per half-wave, L1-hit)
        int cb = c0 + 4 * hi;
        float4 sqA[4];
#pragma unroll
        for (int g4 = 0; g4 < 4; ++g4)
            sqA[g4] = *(const float4*)(&sq[bglob + cb + g4 * 8]);
        int bgc = bglob + cb;            // GLOBAL col id base

        // site loop: s' = sq_col - 2 x.y (sq_row dropped: rank-invariant)
#pragma unroll
        for (int reg = 0; reg < 16; ++reg) {
            float s = fmaf(-2.f, acc0[reg] + acc1[reg],
                           ((const float*)&sqA[reg >> 2])[reg & 3]);
            if (__any(qn == QCAP)) { DRAIN_Q }   // wave-uniform, rare (~14/wave)
            bool pass = s < tv[15];
            if (pass) {
                int cid = bgc + (reg & 3) + 8 * (reg >> 2);
                unsigned long long kk =
                    ((unsigned long long)__float_as_uint(s) << 32) | (unsigned)cid;
                q[qn * 256 + tid] = kk;
                qn += 1;
            }
        }
    }

    // final drain (wave-uniform; qn <= QCAP)
    DRAIN_Q

    __syncthreads();   // queue region dead everywhere -> safe to alias as fink

    // ---- block-end merge: 4 lists/row -> 1 list/row via u64 keys ----
    {
        int rowl = 32 * wr + rloc;
        int li = wc * 2 + hi;            // list index 0..3
#pragma unroll
        for (int j = 0; j < 16; ++j)
            fink[rowl][li * 16 + j] =
                ((unsigned long long)monof(tv[j]) << 32) | (unsigned)ti[j];
    }
    __syncthreads();
    if (tid < 128) {                     // stage 1: merge list pairs (0,1) and (2,3)
        int row = tid & 63, pr = tid >> 6;
        int base = pr * 32;
        unsigned long long tk[16];
#pragma unroll
        for (int j = 0; j < 16; ++j) tk[j] = fink[row][base + j];
        unsigned long long worstk = tk[0];
#pragma unroll
        for (int j = 1; j < 16; ++j) worstk = (tk[j] > worstk) ? tk[j] : worstk;
        for (int e = 0; e < 16; ++e) {
            unsigned long long k = fink[row][base + 16 + e];
            if (k < worstk) {
                unsigned long long mx = tk[0]; int pos = 0;
#pragma unroll
                for (int j = 1; j < 16; ++j) {
                    bool g = tk[j] > mx; mx = g ? tk[j] : mx; pos = g ? j : pos;
                }
#pragma unroll
                for (int j = 0; j < 16; ++j)
                    if (j == pos) tk[j] = k;
                unsigned long long nw = tk[0];
#pragma unroll
                for (int j = 1; j < 16; ++j) nw = (tk[j] > nw) ? tk[j] : nw;
                worstk = nw;
            }
        }
#pragma unroll
        for (int j = 0; j < 16; ++j) fink[row][base + j] = tk[j];
    }
    __syncthreads();
    if (tid < 64) {                      // stage 2: merge (0+1) with (2+3), write out
        int row = tid;
        unsigned long long tk[16];
#pragma unroll
        for (int j = 0; j < 16; ++j) tk[j] = fink[row][j];
        unsigned long long worstk = tk[0];
#pragma unroll
        for (int j = 1; j < 16; ++j) worstk = (tk[j] > worstk) ? tk[j] : worstk;
        for (int e = 0; e < 16; ++e) {
            unsigned long long k = fink[row][32 + e];
            if (k < worstk) {
                unsigned long long mx = tk[0]; int pos = 0;
#pragma unroll
                for (int j = 1; j < 16; ++j) {
                    bool g = tk[j] > mx; mx = g ? tk[j] : mx; pos = g ? j : pos;
                }
#pragma unroll
                for (int j = 0; j < 16; ++j)
                    if (j == pos) tk[j] = k;
                unsigned long long nw = tk[0];
#pragma unroll
                for (int j = 1; j < 16; ++j) nw = (tk[j] > nw) ? tk[j] : nw;
                worstk = nw;
            }
        }
        size_t o = (((size_t)(bglob + r0 + row)) * NQ + half) * KNN;
#pragma unroll
        for (int j = 0; j < 16; ++j) {
            pv[o + j] = invmonof((unsigned)(tk[j] >> 32));
            pi[o + j] = (int)(unsigned)(tk[j] & 0xFFFFFFFFu);
        }
    }
}

// ---------------------------------------------------------------------------
// K1b: merge NQ=2 partial top-16 lists per row -> final idx (u64-key exact).
// ---------------------------------------------------------------------------
__global__ void merge_kernel(const float* __restrict__ pv, const int* __restrict__ pi,
                             int* __restrict__ idx_out) {
    __shared__ unsigned long long mk[128 * 33];
    int tid = threadIdx.x;
    int lr = tid & 127, q = tid >> 7;
    int row = blockIdx.x * 128 + lr;
    size_t o = ((size_t)row * NQ + q) * KNN;
#pragma unroll
    for (int j = 0; j < 16; ++j) {
        mk[lr * 33 + q * 16 + j] =
            ((unsigned long long)monof(pv[o + j]) << 32) | (unsigned)pi[o + j];
    }
    __syncthreads();
    if (tid < 128) {
        unsigned long long tk[16];
#pragma unroll
        for (int j = 0; j < 16; ++j) tk[j] = mk[tid * 33 + j];
        unsigned long long worstk = tk[0];
#pragma unroll
        for (int j = 1; j < 16; ++j) worstk = (tk[j] > worstk) ? tk[j] : worstk;
        for (int e = 16; e < 32; ++e) {
            unsigned long long k = mk[tid * 33 + e];
            if (k < worstk) {
                unsigned long long mx = tk[0]; int pos = 0;
#pragma unroll
                for (int j = 1; j < 16; ++j) {
                    bool g = tk[j] > mx; mx = g ? tk[j] : mx; pos = g ? j : pos;
                }
#pragma unroll
                for (int j = 0; j < 16; ++j)
                    if (j == pos) tk[j] = k;
                unsigned long long nw = tk[0];
#pragma unroll
                for (int j = 1; j < 16; ++j) nw = (tk[j] > nw) ? tk[j] : nw;
                worstk = nw;
            }
        }
        size_t oo = (size_t)tid * KNN + (size_t)blockIdx.x * 128 * KNN;
#pragma unroll
        for (int j = 0; j < 16; ++j)
            idx_out[oo + j] = (int)(unsigned)(tk[j] & 0xFFFFFFFFu);
    }
}

// ---------------------------------------------------------------------------
// K2: U = x @ (W1 - W2), V = x @ W2
// ---------------------------------------------------------------------------
__global__ void prep_UV(const float* __restrict__ x, const float* __restrict__ W,
                        float* __restrict__ U, float* __restrict__ V) {
    __shared__ float Ws[128][64];
    __shared__ float xs[4][64];
    int tid = threadIdx.x;
    for (int i = tid; i < 128 * 64; i += 256) ((float*)Ws)[i] = W[i];
    int p0 = blockIdx.x * 4;
    int r = tid >> 6, c = tid & 63;
    xs[r][c] = x[(size_t)(p0 + r) * C + c];
    __syncthreads();
    float u = 0.f, v = 0.f;
#pragma unroll
    for (int k = 0; k < 64; ++k) {
        float xv = xs[r][k];
        float w1 = Ws[k][c];
        float w2 = Ws[64 + k][c];
        u = fmaf(xv, w1 - w2, u);
        v = fmaf(xv, w2, v);
    }
    size_t o = (size_t)(p0 + r) * C + c;
    U[o] = u;
    V[o] = v;
}

// ---------------------------------------------------------------------------
// K3: BN stats
// ---------------------------------------------------------------------------
__global__ void stats_kernel(const float* __restrict__ U, const float* __restrict__ V,
                             const float* __restrict__ bias, const int* __restrict__ idx,
                             float* __restrict__ stats) {
    int tid = threadIdx.x;
    int c = tid & 63, kk = tid >> 6;
    int p0 = blockIdx.x * 32;
    float bc = bias[c];
    float sum = 0.f, sumsq = 0.f;
    for (int pp = 0; pp < 32; ++pp) {
        int p = p0 + pp;
        float u = U[(size_t)p * C + c] + bc;
#pragma unroll
        for (int k4 = 0; k4 < 4; ++k4) {
            int j = idx[(size_t)p * KNN + kk * 4 + k4];
            float h = u + V[(size_t)j * C + c];
            sum += h;
            sumsq = fmaf(h, h, sumsq);
        }
    }
    __shared__ float red[2][4][64];
    red[0][kk][c] = sum;
    red[1][kk][c] = sumsq;
    __syncthreads();
    if (tid < 64) {
        float s = red[0][0][tid] + red[0][1][tid] + red[0][2][tid] + red[0][3][tid];
        atomicAdd(&stats[tid], s);
    } else if (tid < 128) {
        int cc = tid - 64;
        float s = red[1][0][cc] + red[1][1][cc] + red[1][2][cc] + red[1][3][cc];
        atomicAdd(&stats[64 + cc], s);
    }
}

__global__ void finalize_kernel(const float* __restrict__ stats,
                                const float* __restrict__ gamma,
                                const float* __restrict__ beta,
                                float* __restrict__ sshift) {
    int c = threadIdx.x;
    const float N = (float)NEDGE;
    float mean = stats[c] / N;
    float var = stats[64 + c] / N - mean * mean;
    float s = gamma[c] * rsqrtf(var + EPSV);
    sshift[c] = s;
    sshift[64 + c] = beta[c] - mean * s;
}

// ---------------------------------------------------------------------------
// K5: out = lrelu(s*(U+b + max/min_k V[idx]) + t)  (monotone fusion of max_k)
// ---------------------------------------------------------------------------
__global__ void out_kernel(const float* __restrict__ U, const float* __restrict__ V,
                           const float* __restrict__ bias, const int* __restrict__ idx,
                           const float* __restrict__ sshift, float* __restrict__ out) {
    int tid = threadIdx.x;
    int c = tid & 63, g = tid >> 6;
    int p0 = blockIdx.x * 16;
    float s = sshift[c], t = sshift[64 + c];
    float bc = bias[c];
    for (int pp = g; pp < 16; pp += 4) {
        int p = p0 + pp;
        float mx = -FLT_MAX, mn = FLT_MAX;
#pragma unroll
        for (int k = 0; k < KNN; ++k) {
            int j = idx[(size_t)p * KNN + k];
            float v = V[(size_t)j * C + c];
            mx = fmaxf(mx, v);
            mn = fminf(mn, v);
        }
        float hsel = (s >= 0.f) ? mx : mn;
        float hn = fmaf(s, U[(size_t)p * C + c] + bc + hsel, t);
        out[(size_t)p * C + c] = (hn >= 0.f) ? hn : SLOPE * hn;
    }
}

// ---------------------------------------------------------------------------
extern "C" void kernel_launch(void* const* d_in, const int* in_sizes, int n_in,
                              void* d_out, int out_size, void* d_ws, size_t ws_size,
                              hipStream_t stream) {
    const float* x     = (const float*)d_in[0];
    const float* W     = (const float*)d_in[2];
    const float* bias  = (const float*)d_in[3];
    const float* gamma = (const float*)d_in[4];
    const float* beta  = (const float*)d_in[5];
    float* out = (float*)d_out;

    float* wsf    = (float*)d_ws;
    float* U      = wsf;
    float* V      = wsf + 2097152;
    uint4* xfh    = (uint4*)wsf;                   // aliases U/V, dead after knn
    uint4* xfm    = (uint4*)(wsf + 1048576);
    uint4* xfl    = (uint4*)(wsf + 2097152);
    float* sq     = wsf + 4194304;
    float* stats  = wsf + 4227072;
    float* sshift = wsf + 4227200;
    int*   idx    = (int*)(wsf + 4227328);
    float* pv     = wsf + 4751616;
    int*   pi     = (int*)(wsf + 5800192);

    hipLaunchKernelGGL(prep_frag, dim3(NPTS / 32), dim3(256), 0, stream, x, xfh, xfm, xfl, sq);
    hipLaunchKernelGGL(knn_kernel, dim3(BATCH * (P / 64) * NQ), dim3(256), 0, stream,
                       (const uint4*)xfh, (const uint4*)xfm, (const uint4*)xfl, sq, pv, pi);
    hipLaunchKernelGGL(merge_kernel, dim3(NPTS / 128), dim3(256), 0, stream, pv, pi, idx);
    hipLaunchKernelGGL(prep_UV, dim3(NPTS / 4), dim3(256), 0, stream, x, W, U, V);
    hipMemsetAsync(stats, 0, 128 * sizeof(float), stream);
    hipLaunchKernelGGL(stats_kernel, dim3(NPTS / 32), dim3(256), 0, stream, U, V, bias, idx, stats);
    hipLaunchKernelGGL(finalize_kernel, dim3(1), dim3(64), 0, stream, stats, gamma, beta, sshift);
    hipLaunchKernelGGL(out_kernel, dim3(NPTS / 16), dim3(256), 0, stream, U, V, bias, idx, sshift, out);
}